// Round 1
// baseline (457.598 us; speedup 1.0000x reference)
//
#include <hip/hip_runtime.h>

// ---------------- degree / CSR build ----------------

__global__ void count_dst(const int* __restrict__ dst, int E, int* __restrict__ cnt) {
    int e = blockIdx.x * blockDim.x + threadIdx.x;
    if (e < E) atomicAdd(&cnt[dst[e]], 1);
}

__global__ void compute_dis(const int* __restrict__ cnt, float* __restrict__ dis, int n) {
    int i = blockIdx.x * blockDim.x + threadIdx.x;
    if (i < n) dis[i] = rsqrtf((float)(cnt[i] + 1));  // +1 self-loop
}

// block scans 1024 elements (256 thr x 4); writes local-exclusive scan + block total
__global__ __launch_bounds__(256) void scanA(const int* __restrict__ cnt,
                                             int* __restrict__ row_ptr,
                                             int* __restrict__ blockSums, int n) {
    __shared__ int s[256];
    int t = threadIdx.x;
    int base = blockIdx.x * 1024 + t * 4;
    int v0 = (base + 0 < n) ? cnt[base + 0] : 0;
    int v1 = (base + 1 < n) ? cnt[base + 1] : 0;
    int v2 = (base + 2 < n) ? cnt[base + 2] : 0;
    int v3 = (base + 3 < n) ? cnt[base + 3] : 0;
    int tsum = v0 + v1 + v2 + v3;
    s[t] = tsum;
    __syncthreads();
    for (int off = 1; off < 256; off <<= 1) {
        int u = (t >= off) ? s[t - off] : 0;
        __syncthreads();
        s[t] += u;
        __syncthreads();
    }
    int excl = s[t] - tsum;
    if (base + 0 < n) row_ptr[base + 0] = excl;
    if (base + 1 < n) row_ptr[base + 1] = excl + v0;
    if (base + 2 < n) row_ptr[base + 2] = excl + v0 + v1;
    if (base + 3 < n) row_ptr[base + 3] = excl + v0 + v1 + v2;
    if (t == 255) blockSums[blockIdx.x] = s[255];
}

// single wave scans <=64 block sums -> exclusive offsets
__global__ void scanB(const int* __restrict__ blockSums, int* __restrict__ blockOff, int B) {
    int t = threadIdx.x;  // 64 threads
    int v = (t < B) ? blockSums[t] : 0;
    int orig = v;
    for (int off = 1; off < 64; off <<= 1) {
        int u = __shfl_up(v, off, 64);
        if (t >= off) v += u;
    }
    if (t < B) blockOff[t] = v - orig;
}

__global__ __launch_bounds__(256) void scanC(int* __restrict__ row_ptr,
                                             const int* __restrict__ blockOff, int n, int E) {
    int base = blockIdx.x * 1024 + threadIdx.x * 4;
    int off = blockOff[blockIdx.x];
    #pragma unroll
    for (int j = 0; j < 4; ++j)
        if (base + j < n) row_ptr[base + j] += off;
    if (blockIdx.x == 0 && threadIdx.x == 0) row_ptr[n] = E;
}

__global__ void fill_csr(const int* __restrict__ src, const int* __restrict__ dst, int E,
                         const int* __restrict__ row_ptr, int* __restrict__ fillc,
                         const float* __restrict__ dis,
                         int* __restrict__ csr_src, float* __restrict__ csr_coef) {
    int e = blockIdx.x * blockDim.x + threadIdx.x;
    if (e >= E) return;
    int d = dst[e], s = src[e];
    int ofs = atomicAdd(&fillc[d], 1);
    int slot = row_ptr[d] + ofs;
    csr_src[slot] = s;
    csr_coef[slot] = dis[s] * dis[d];
}

// ---------------- GEMM: Y[M,N] = X[M,128] @ W[128,N] (no bias/act) ----------------

template <int N>
__global__ __launch_bounds__(256) void gemm_k128(const float* __restrict__ X,
                                                 const float* __restrict__ W,
                                                 float* __restrict__ Y, int M) {
    constexpr int RPT = N / 16;  // 8 rows/thread (N=128) or 4 (N=64)
    constexpr int CG = N / 4;    // float4 col groups: 32 or 16
    __shared__ float Ws[128 * N];
    __shared__ float Xs[64 * 128];
    int t = threadIdx.x;
    int m0 = blockIdx.x * 64;
    for (int j = t * 4; j < 128 * N; j += 1024)
        *(float4*)&Ws[j] = *(const float4*)&W[j];
    for (int j = t * 4; j < 64 * 128; j += 1024) {
        int row = m0 + (j >> 7);
        float4 v = (row < M) ? *(const float4*)&X[row * 128 + (j & 127)]
                             : float4{0.f, 0.f, 0.f, 0.f};
        *(float4*)&Xs[j] = v;
    }
    __syncthreads();
    int mc = t % CG;
    int mr = t / CG;
    float acc[RPT][4] = {};
    const float* xbase = &Xs[(mr * RPT) * 128];
    for (int k = 0; k < 128; ++k) {
        float4 w = *(const float4*)&Ws[k * N + mc * 4];
        #pragma unroll
        for (int r = 0; r < RPT; ++r) {
            float xv = xbase[r * 128 + k];
            acc[r][0] += xv * w.x;
            acc[r][1] += xv * w.y;
            acc[r][2] += xv * w.z;
            acc[r][3] += xv * w.w;
        }
    }
    #pragma unroll
    for (int r = 0; r < RPT; ++r) {
        int row = m0 + mr * RPT + r;
        if (row < M) *(float4*)&Y[row * N + mc * 4] = *(float4*)&acc[r][0];
    }
}

// ---------------- aggregation: out[i] = relu(b + dis[i]^2*h[i] + sum coef*h[src]) ----------------

template <int D>
__global__ __launch_bounds__(256) void agg_gcn(const float* __restrict__ h,
                                               const int* __restrict__ row_ptr,
                                               const int* __restrict__ csr_src,
                                               const float* __restrict__ csr_coef,
                                               const float* __restrict__ dis,
                                               const float* __restrict__ bias,
                                               float* __restrict__ out, int n) {
    int wid = (blockIdx.x * 256 + threadIdx.x) >> 6;
    if (wid >= n) return;
    int lane = threadIdx.x & 63;
    int beg = row_ptr[wid], end = row_ptr[wid + 1];
    float di = dis[wid];
    float cs = di * di;
    if constexpr (D == 128) {
        const float2* hp = (const float2*)h;
        float2 sv = hp[(size_t)wid * 64 + lane];
        float2 a0 = {cs * sv.x, cs * sv.y};
        float2 a1 = {0.f, 0.f};
        int e = beg;
        for (; e + 2 <= end; e += 2) {
            int s0 = csr_src[e], s1 = csr_src[e + 1];
            float c0 = csr_coef[e], c1 = csr_coef[e + 1];
            float2 u0 = hp[(size_t)s0 * 64 + lane];
            float2 u1 = hp[(size_t)s1 * 64 + lane];
            a0.x += c0 * u0.x; a0.y += c0 * u0.y;
            a1.x += c1 * u1.x; a1.y += c1 * u1.y;
        }
        if (e < end) {
            int s0 = csr_src[e];
            float c0 = csr_coef[e];
            float2 u0 = hp[(size_t)s0 * 64 + lane];
            a0.x += c0 * u0.x; a0.y += c0 * u0.y;
        }
        float2 bv = ((const float2*)bias)[lane];
        float2 o;
        o.x = fmaxf(a0.x + a1.x + bv.x, 0.f);
        o.y = fmaxf(a0.y + a1.y + bv.y, 0.f);
        ((float2*)out)[(size_t)wid * 64 + lane] = o;
    } else {
        float a0 = cs * h[(size_t)wid * 64 + lane];
        float a1 = 0.f;
        int e = beg;
        for (; e + 2 <= end; e += 2) {
            int s0 = csr_src[e], s1 = csr_src[e + 1];
            float c0 = csr_coef[e], c1 = csr_coef[e + 1];
            a0 += c0 * h[(size_t)s0 * 64 + lane];
            a1 += c1 * h[(size_t)s1 * 64 + lane];
        }
        if (e < end) a0 += csr_coef[e] * h[(size_t)csr_src[e] * 64 + lane];
        float o = fmaxf(a0 + a1 + bias[lane], 0.f);
        out[(size_t)wid * 64 + lane] = o;
    }
}

// ---------------- projection + relu + row-normalize (in place on d_out) ----------------

__global__ __launch_bounds__(256) void proj_norm(float* __restrict__ P,
                                                 const float* __restrict__ Wp, int n) {
    __shared__ float Ws[64 * 64];
    int t = threadIdx.x;
    for (int j = t * 4; j < 4096; j += 1024)
        *(float4*)&Ws[j] = *(const float4*)&Wp[j];
    __syncthreads();
    int wid = (blockIdx.x * 256 + t) >> 6;
    if (wid >= n) return;
    int lane = t & 63;
    float hv = P[(size_t)wid * 64 + lane];
    float acc = 0.f;
    #pragma unroll
    for (int k = 0; k < 64; ++k) {
        float xv = __shfl(hv, k, 64);
        acc += xv * Ws[k * 64 + lane];
    }
    acc = fmaxf(acc, 0.f);
    float ss = acc * acc;
    #pragma unroll
    for (int off = 32; off; off >>= 1) ss += __shfl_xor(ss, off, 64);
    float norm = sqrtf(ss);
    float scale = 1.0f / fmaxf(norm, 1e-12f);
    P[(size_t)wid * 64 + lane] = acc * scale;
}

// ---------------- launch ----------------

static inline size_t ws_align(size_t x) { return (x + 255) & ~(size_t)255; }

extern "C" void kernel_launch(void* const* d_in, const int* in_sizes, int n_in,
                              void* d_out, int out_size, void* d_ws, size_t ws_size,
                              hipStream_t stream) {
    const float* x  = (const float*)d_in[0];
    const int*   ei = (const int*)d_in[1];
    const float* W1 = (const float*)d_in[2];
    const float* b1 = (const float*)d_in[3];
    const float* W2 = (const float*)d_in[4];
    const float* b2 = (const float*)d_in[5];
    const float* W3 = (const float*)d_in[6];
    const float* b3 = (const float*)d_in[7];
    const float* Wp = (const float*)d_in[8];

    int n = in_sizes[0] / 128;
    int E = in_sizes[1] / 2;
    const int* src = ei;
    const int* dst = ei + E;

    char* ws = (char*)d_ws;
    size_t off = 0;
    auto alloc = [&](size_t bytes) -> void* {
        void* p = ws + off;
        off = ws_align(off + bytes);
        return p;
    };
    float* bufA     = (float*)alloc((size_t)n * 128 * 4);
    float* bufB     = (float*)alloc((size_t)n * 128 * 4);
    int*   cnt      = (int*)alloc((size_t)n * 4);
    int*   fillc    = (int*)alloc((size_t)n * 4);
    float* dis      = (float*)alloc((size_t)n * 4);
    int*   row_ptr  = (int*)alloc((size_t)(n + 1) * 4);
    int*   csr_src  = (int*)alloc((size_t)E * 4);
    float* csr_coef = (float*)alloc((size_t)E * 4);
    int*   blockSums = (int*)alloc(256);
    int*   blockOff  = (int*)alloc(256);
    (void)off; (void)ws_size;

    hipMemsetAsync(cnt, 0, (size_t)n * 4, stream);
    hipMemsetAsync(fillc, 0, (size_t)n * 4, stream);

    int B = (n + 1023) / 1024;
    count_dst<<<(E + 255) / 256, 256, 0, stream>>>(dst, E, cnt);
    compute_dis<<<(n + 255) / 256, 256, 0, stream>>>(cnt, dis, n);
    scanA<<<B, 256, 0, stream>>>(cnt, row_ptr, blockSums, n);
    scanB<<<1, 64, 0, stream>>>(blockSums, blockOff, B);
    scanC<<<B, 256, 0, stream>>>(row_ptr, blockOff, n, E);
    fill_csr<<<(E + 255) / 256, 256, 0, stream>>>(src, dst, E, row_ptr, fillc, dis,
                                                  csr_src, csr_coef);

    int gblocks = (n + 63) / 64;
    int ablocks = (n + 3) / 4;
    float* outp = (float*)d_out;

    gemm_k128<128><<<gblocks, 256, 0, stream>>>(x, W1, bufA, n);
    agg_gcn<128><<<ablocks, 256, 0, stream>>>(bufA, row_ptr, csr_src, csr_coef, dis, b1, bufB, n);
    gemm_k128<128><<<gblocks, 256, 0, stream>>>(bufB, W2, bufA, n);
    agg_gcn<128><<<ablocks, 256, 0, stream>>>(bufA, row_ptr, csr_src, csr_coef, dis, b2, bufB, n);
    gemm_k128<64><<<gblocks, 256, 0, stream>>>(bufB, W3, bufA, n);
    agg_gcn<64><<<ablocks, 256, 0, stream>>>(bufA, row_ptr, csr_src, csr_coef, dis, b3, outp, n);
    proj_norm<<<ablocks, 256, 0, stream>>>(outp, Wp, n);
}

// Round 2
// 389.098 us; speedup vs baseline: 1.1760x; 1.1760x over previous
//
#include <hip/hip_runtime.h>

// ---------------- degree / CSR build ----------------

__global__ void count_dst(const int* __restrict__ dst, int E, int* __restrict__ cnt) {
    int e = blockIdx.x * blockDim.x + threadIdx.x;
    if (e < E) atomicAdd(&cnt[dst[e]], 1);
}

__global__ void compute_dis(const int* __restrict__ cnt, float* __restrict__ dis, int n) {
    int i = blockIdx.x * blockDim.x + threadIdx.x;
    if (i < n) dis[i] = rsqrtf((float)(cnt[i] + 1));  // +1 self-loop
}

// block scans 1024 elements (256 thr x 4); writes local-exclusive scan + block total
__global__ __launch_bounds__(256) void scanA(const int* __restrict__ cnt,
                                             int* __restrict__ row_ptr,
                                             int* __restrict__ blockSums, int n) {
    __shared__ int s[256];
    int t = threadIdx.x;
    int base = blockIdx.x * 1024 + t * 4;
    int v0 = (base + 0 < n) ? cnt[base + 0] : 0;
    int v1 = (base + 1 < n) ? cnt[base + 1] : 0;
    int v2 = (base + 2 < n) ? cnt[base + 2] : 0;
    int v3 = (base + 3 < n) ? cnt[base + 3] : 0;
    int tsum = v0 + v1 + v2 + v3;
    s[t] = tsum;
    __syncthreads();
    for (int off = 1; off < 256; off <<= 1) {
        int u = (t >= off) ? s[t - off] : 0;
        __syncthreads();
        s[t] += u;
        __syncthreads();
    }
    int excl = s[t] - tsum;
    if (base + 0 < n) row_ptr[base + 0] = excl;
    if (base + 1 < n) row_ptr[base + 1] = excl + v0;
    if (base + 2 < n) row_ptr[base + 2] = excl + v0 + v1;
    if (base + 3 < n) row_ptr[base + 3] = excl + v0 + v1 + v2;
    if (t == 255) blockSums[blockIdx.x] = s[255];
}

// single wave scans <=64 block sums -> exclusive offsets
__global__ void scanB(const int* __restrict__ blockSums, int* __restrict__ blockOff, int B) {
    int t = threadIdx.x;  // 64 threads
    int v = (t < B) ? blockSums[t] : 0;
    int orig = v;
    for (int off = 1; off < 64; off <<= 1) {
        int u = __shfl_up(v, off, 64);
        if (t >= off) v += u;
    }
    if (t < B) blockOff[t] = v - orig;
}

__global__ __launch_bounds__(256) void scanC(int* __restrict__ row_ptr,
                                             const int* __restrict__ blockOff, int n, int E) {
    int base = blockIdx.x * 1024 + threadIdx.x * 4;
    int off = blockOff[blockIdx.x];
    #pragma unroll
    for (int j = 0; j < 4; ++j)
        if (base + j < n) row_ptr[base + j] += off;
    if (blockIdx.x == 0 && threadIdx.x == 0) row_ptr[n] = E;
}

// edges[slot] = { src, bitcast(coef) } — single 8B scattered store per edge
__global__ void fill_csr(const int* __restrict__ src, const int* __restrict__ dst, int E,
                         const int* __restrict__ row_ptr, int* __restrict__ fillc,
                         const float* __restrict__ dis,
                         int2* __restrict__ edges) {
    int e = blockIdx.x * blockDim.x + threadIdx.x;
    if (e >= E) return;
    int d = dst[e], s = src[e];
    int ofs = atomicAdd(&fillc[d], 1);
    int slot = row_ptr[d] + ofs;
    float coef = dis[s] * dis[d];
    edges[slot] = make_int2(s, __float_as_int(coef));
}

// ---------------- GEMM: Y[M,N] = X[M,128] @ W[128,N] ----------------
// Only X tile staged in LDS (32KB); W streamed from global (L2-resident).

template <int N>
__global__ __launch_bounds__(256) void gemm_k128(const float* __restrict__ X,
                                                 const float* __restrict__ W,
                                                 float* __restrict__ Y, int M) {
    constexpr int CG = N / 4;         // float4 col groups: 32 (N=128) or 16 (N=64)
    constexpr int RG = 256 / CG;      // row groups: 8 or 16
    constexpr int RPT = 64 / RG;      // rows per thread: 8 or 4
    __shared__ float Xs[64 * 128];    // 32 KB
    int t = threadIdx.x;
    int m0 = blockIdx.x * 64;
    for (int j = t * 4; j < 64 * 128; j += 1024) {
        int row = m0 + (j >> 7);
        float4 v = (row < M) ? *(const float4*)&X[(size_t)row * 128 + (j & 127)]
                             : float4{0.f, 0.f, 0.f, 0.f};
        *(float4*)&Xs[j] = v;
    }
    __syncthreads();
    int mc = t % CG;
    int mr = t / CG;
    float acc[RPT][4] = {};
    const float* xbase = &Xs[(mr * RPT) * 128];
    const float* wp = W + mc * 4;
    #pragma unroll 4
    for (int k = 0; k < 128; ++k) {
        float4 w = *(const float4*)&wp[k * N];
        #pragma unroll
        for (int r = 0; r < RPT; ++r) {
            float xv = xbase[r * 128 + k];
            acc[r][0] += xv * w.x;
            acc[r][1] += xv * w.y;
            acc[r][2] += xv * w.z;
            acc[r][3] += xv * w.w;
        }
    }
    #pragma unroll
    for (int r = 0; r < RPT; ++r) {
        int row = m0 + mr * RPT + r;
        if (row < M) *(float4*)&Y[(size_t)row * N + mc * 4] = *(float4*)&acc[r][0];
    }
}

// ---------------- aggregation: out[i] = relu(b + dis[i]^2*h[i] + sum coef*h[src]) ----------------

template <int D>
__global__ __launch_bounds__(256) void agg_gcn(const float* __restrict__ h,
                                               const int* __restrict__ row_ptr,
                                               const int2* __restrict__ edges,
                                               const float* __restrict__ dis,
                                               const float* __restrict__ bias,
                                               float* __restrict__ out, int n) {
    int wid = (blockIdx.x * 256 + threadIdx.x) >> 6;
    if (wid >= n) return;
    int lane = threadIdx.x & 63;
    int beg = row_ptr[wid], end = row_ptr[wid + 1];
    float di = dis[wid];
    float cs = di * di;
    if constexpr (D == 128) {
        const float2* hp = (const float2*)h;
        float2 sv = hp[(size_t)wid * 64 + lane];
        float2 a0 = {cs * sv.x, cs * sv.y};
        float2 a1 = {0.f, 0.f}, a2 = {0.f, 0.f}, a3 = {0.f, 0.f};
        int e = beg;
        for (; e + 4 <= end; e += 4) {
            int2 e0 = edges[e], e1 = edges[e + 1], e2 = edges[e + 2], e3 = edges[e + 3];
            float2 u0 = hp[(size_t)e0.x * 64 + lane];
            float2 u1 = hp[(size_t)e1.x * 64 + lane];
            float2 u2 = hp[(size_t)e2.x * 64 + lane];
            float2 u3 = hp[(size_t)e3.x * 64 + lane];
            float c0 = __int_as_float(e0.y), c1 = __int_as_float(e1.y);
            float c2 = __int_as_float(e2.y), c3 = __int_as_float(e3.y);
            a0.x += c0 * u0.x; a0.y += c0 * u0.y;
            a1.x += c1 * u1.x; a1.y += c1 * u1.y;
            a2.x += c2 * u2.x; a2.y += c2 * u2.y;
            a3.x += c3 * u3.x; a3.y += c3 * u3.y;
        }
        for (; e < end; ++e) {
            int2 e0 = edges[e];
            float c0 = __int_as_float(e0.y);
            float2 u0 = hp[(size_t)e0.x * 64 + lane];
            a0.x += c0 * u0.x; a0.y += c0 * u0.y;
        }
        float2 bv = ((const float2*)bias)[lane];
        float2 o;
        o.x = fmaxf(a0.x + a1.x + a2.x + a3.x + bv.x, 0.f);
        o.y = fmaxf(a0.y + a1.y + a2.y + a3.y + bv.y, 0.f);
        ((float2*)out)[(size_t)wid * 64 + lane] = o;
    } else {
        float a0 = cs * h[(size_t)wid * 64 + lane];
        float a1 = 0.f, a2 = 0.f, a3 = 0.f;
        int e = beg;
        for (; e + 4 <= end; e += 4) {
            int2 e0 = edges[e], e1 = edges[e + 1], e2 = edges[e + 2], e3 = edges[e + 3];
            a0 += __int_as_float(e0.y) * h[(size_t)e0.x * 64 + lane];
            a1 += __int_as_float(e1.y) * h[(size_t)e1.x * 64 + lane];
            a2 += __int_as_float(e2.y) * h[(size_t)e2.x * 64 + lane];
            a3 += __int_as_float(e3.y) * h[(size_t)e3.x * 64 + lane];
        }
        for (; e < end; ++e)
            a0 += __int_as_float(edges[e].y) * h[(size_t)edges[e].x * 64 + lane];
        float o = fmaxf(a0 + a1 + a2 + a3 + bias[lane], 0.f);
        out[(size_t)wid * 64 + lane] = o;
    }
}

// ---------------- projection + relu + row-normalize (in place on d_out) ----------------

__global__ __launch_bounds__(256) void proj_norm(float* __restrict__ P,
                                                 const float* __restrict__ Wp, int n) {
    __shared__ float Ws[64 * 64];
    int t = threadIdx.x;
    for (int j = t * 4; j < 4096; j += 1024)
        *(float4*)&Ws[j] = *(const float4*)&Wp[j];
    __syncthreads();
    int wid = (blockIdx.x * 256 + t) >> 6;
    if (wid >= n) return;
    int lane = t & 63;
    float hv = P[(size_t)wid * 64 + lane];
    float acc = 0.f;
    #pragma unroll
    for (int k = 0; k < 64; ++k) {
        float xv = __shfl(hv, k, 64);
        acc += xv * Ws[k * 64 + lane];
    }
    acc = fmaxf(acc, 0.f);
    float ss = acc * acc;
    #pragma unroll
    for (int off = 32; off; off >>= 1) ss += __shfl_xor(ss, off, 64);
    float norm = sqrtf(ss);
    float scale = 1.0f / fmaxf(norm, 1e-12f);
    P[(size_t)wid * 64 + lane] = acc * scale;
}

// ---------------- launch ----------------

static inline size_t ws_align(size_t x) { return (x + 255) & ~(size_t)255; }

extern "C" void kernel_launch(void* const* d_in, const int* in_sizes, int n_in,
                              void* d_out, int out_size, void* d_ws, size_t ws_size,
                              hipStream_t stream) {
    const float* x  = (const float*)d_in[0];
    const int*   ei = (const int*)d_in[1];
    const float* W1 = (const float*)d_in[2];
    const float* b1 = (const float*)d_in[3];
    const float* W2 = (const float*)d_in[4];
    const float* b2 = (const float*)d_in[5];
    const float* W3 = (const float*)d_in[6];
    const float* b3 = (const float*)d_in[7];
    const float* Wp = (const float*)d_in[8];

    int n = in_sizes[0] / 128;
    int E = in_sizes[1] / 2;
    const int* src = ei;
    const int* dst = ei + E;

    char* ws = (char*)d_ws;
    size_t off = 0;
    auto alloc = [&](size_t bytes) -> void* {
        void* p = ws + off;
        off = ws_align(off + bytes);
        return p;
    };
    float* bufA     = (float*)alloc((size_t)n * 128 * 4);
    float* bufB     = (float*)alloc((size_t)n * 128 * 4);
    int*   cnt      = (int*)alloc((size_t)n * 4);
    int*   fillc    = (int*)alloc((size_t)n * 4);
    float* dis      = (float*)alloc((size_t)n * 4);
    int*   row_ptr  = (int*)alloc((size_t)(n + 1) * 4);
    int2*  edges    = (int2*)alloc((size_t)E * 8);
    int*   blockSums = (int*)alloc(256);
    int*   blockOff  = (int*)alloc(256);
    (void)off; (void)ws_size;

    hipMemsetAsync(cnt, 0, (size_t)n * 4, stream);
    hipMemsetAsync(fillc, 0, (size_t)n * 4, stream);

    int B = (n + 1023) / 1024;
    count_dst<<<(E + 255) / 256, 256, 0, stream>>>(dst, E, cnt);
    compute_dis<<<(n + 255) / 256, 256, 0, stream>>>(cnt, dis, n);
    scanA<<<B, 256, 0, stream>>>(cnt, row_ptr, blockSums, n);
    scanB<<<1, 64, 0, stream>>>(blockSums, blockOff, B);
    scanC<<<B, 256, 0, stream>>>(row_ptr, blockOff, n, E);
    fill_csr<<<(E + 255) / 256, 256, 0, stream>>>(src, dst, E, row_ptr, fillc, dis, edges);

    int gblocks = (n + 63) / 64;
    int ablocks = (n + 3) / 4;
    float* outp = (float*)d_out;

    gemm_k128<128><<<gblocks, 256, 0, stream>>>(x, W1, bufA, n);
    agg_gcn<128><<<ablocks, 256, 0, stream>>>(bufA, row_ptr, edges, dis, b1, bufB, n);
    gemm_k128<128><<<gblocks, 256, 0, stream>>>(bufB, W2, bufA, n);
    agg_gcn<128><<<ablocks, 256, 0, stream>>>(bufA, row_ptr, edges, dis, b2, bufB, n);
    gemm_k128<64><<<gblocks, 256, 0, stream>>>(bufB, W3, bufA, n);
    agg_gcn<64><<<ablocks, 256, 0, stream>>>(bufA, row_ptr, edges, dis, b3, outp, n);
    proj_norm<<<ablocks, 256, 0, stream>>>(outp, Wp, n);
}